// Round 1
// baseline (233.911 us; speedup 1.0000x reference)
//
#include <hip/hip_runtime.h>
#include <hip/hip_bf16.h>

#define EPS 1e-07f

// Pass 1: fill entire output with EPS (vectorized float4, grid-stride).
__global__ void fill_eps_kernel(float4* __restrict__ out, int n4) {
    int stride = gridDim.x * blockDim.x;
    const float4 v = make_float4(EPS, EPS, EPS, EPS);
    for (int i = blockIdx.x * blockDim.x + threadIdx.x; i < n4; i += stride) {
        out[i] = v;
    }
}

// Pass 2: scatter 1.0f + EPS at each index. All writes store the same value,
// so duplicate indices are benign (no atomics needed).
__global__ void scatter_ones_kernel(const int4* __restrict__ idx, float* __restrict__ out, int n4) {
    int i = blockIdx.x * blockDim.x + threadIdx.x;
    if (i < n4) {
        int4 v = idx[i];
        const float one = 1.0f + EPS;
        out[v.x] = one;
        out[v.y] = one;
        out[v.z] = one;
        out[v.w] = one;
    }
}

extern "C" void kernel_launch(void* const* d_in, const int* in_sizes, int n_in,
                              void* d_out, int out_size, void* d_ws, size_t ws_size,
                              hipStream_t stream) {
    // inputs: [0] voxel (float32, 256^3) -- value-irrelevant to the output
    //         [1] cell_indices (int32, 256^3)
    //         [2] num_elements (scalar) -- use out_size instead
    const int* cell_indices = (const int*)d_in[1];
    float* out = (float*)d_out;

    // Fill: out_size floats -> out_size/4 float4 stores.
    int n4_fill = out_size >> 2;  // 33554432 / 4 = 8388608
    int fill_blocks = 2048;       // grid-stride, ~8 blocks/CU territory
    fill_eps_kernel<<<fill_blocks, 256, 0, stream>>>((float4*)d_out, n4_fill);

    // Scatter: n_idx indices -> n_idx/4 int4 reads.
    int n_idx = in_sizes[1];      // 16777216
    int n4_idx = n_idx >> 2;      // 4194304
    int blocks = (n4_idx + 255) / 256;
    scatter_ones_kernel<<<blocks, 256, 0, stream>>>((const int4*)cell_indices, out, n4_idx);
}